// Round 11
// baseline (135.023 us; speedup 1.0000x reference)
//
#include <hip/hip_runtime.h>
#include <hip/hip_cooperative_groups.h>

namespace cg = cooperative_groups;

#define B_N 4096
#define POOL_N 45
#define PACK_N 15
#define E_N 512
#define V_N 30000

// ws layout (floats):
//   wt  [512][24]  : transposed weights, col j: 0..7=q_w, 8..15=k_w, 16..23=v_w
//   tab [V][24]    : per-card projections, 0..7=q, 8..15=k(relu), 16..23=v(relu)
//   aux [B][32]    : 0..7 k_win, 8..15 v_win, 16..23 k_rank, 24..31 v_rank
#define WT_SZ  (E_N * 24)
#define TAB_SZ (V_N * 24)
#define AUX_SZ (B_N * 32)

// ---------------- shared device bodies (used by fused AND fallback) --------

// transpose (blocks 0..23) + aux (all 256 blocks, 16 b each; 32 e-segs of 16)
__device__ __forceinline__ void body_pre(int blk, int t,
    const float* __restrict__ wins, const float* __restrict__ ranks,
    const float* __restrict__ win_w, const float* __restrict__ win_b,
    const float* __restrict__ rank_w, const float* __restrict__ rank_b,
    const float* __restrict__ q_w, const float* __restrict__ k_w,
    const float* __restrict__ v_w,
    float* __restrict__ wt, float* __restrict__ aux, float* lds) {
  if (blk < 24) {
    int i = blk * 512 + t;  // 24*512 = 12288 = 512*24
    int e = i / 24, j = i % 24;
    float val = (j < 8) ? q_w[j * E_N + e]
              : (j < 16) ? k_w[(j - 8) * E_N + e]
                         : v_w[(j - 16) * E_N + e];
    wt[i] = val;
  }
  int bl = t & 15, seg = t >> 4;  // seg 0..31, 16 e each
  int b = blk * 16 + bl;
  for (int which = 0; which < 2; ++which) {
    float s = which ? ranks[b] : wins[b];
    const float* ww = which ? rank_w : win_w;
    const float* wb = which ? rank_b : win_b;
    float acc[16];
#pragma unroll
    for (int j = 0; j < 16; ++j) acc[j] = 0.f;
    int e0 = seg * 16;
    for (int e = e0; e < e0 + 16; ++e) {
      float x = fmaf(s, ww[e], wb[e]);
      float xr = fmaxf(x, 0.f);
#pragma unroll
      for (int j = 0; j < 8; ++j) acc[j] = fmaf(xr, k_w[j * E_N + e], acc[j]);
#pragma unroll
      for (int j = 0; j < 8; ++j) acc[8 + j] = fmaf(xr, v_w[j * E_N + e], acc[8 + j]);
    }
#pragma unroll
    for (int j = 0; j < 16; ++j) lds[(seg * 16 + bl) * 17 + j] = acc[j];
    __syncthreads();
    if (t < 256) {
      int bi = t >> 4, jj = t & 15;
      float v = 0.f;
#pragma unroll
      for (int sg = 0; sg < 32; ++sg) v += lds[(sg * 16 + bi) * 17 + jj];
      aux[(size_t)(blk * 16 + bi) * 32 + which * 16 + jj] = v;
    }
    __syncthreads();
  }
}

// R3-proven attention body; 16 groups of 32 lanes per 512-thread block.
__device__ __forceinline__ void body_main(int blk, int t,
    const int* __restrict__ pool, const int* __restrict__ pack,
    const float* __restrict__ tab, const float* __restrict__ aux,
    const float* __restrict__ sc_w, const float* __restrict__ sc_b,
    float* __restrict__ out) {
  int grp = t >> 5;
  int lane = t & 31;
  int b = blk * 16 + grp;
  int i0 = pool[(size_t)b * POOL_N + lane];
  int i1 = (lane < POOL_N - 32) ? pool[(size_t)b * POOL_N + 32 + lane] : 0;
  int k = (lane < PACK_N) ? lane : 0;
  int qidx = pack[(size_t)b * PACK_N + k];
  const float* qr = tab + (size_t)qidx * 24;
  float4 qa = *(const float4*)qr;
  float4 qb = *(const float4*)(qr + 4);
  const float rs = 0.35355339059327373f;  // 1/sqrt(8)
  const float* auxb = aux + (size_t)b * 32;

  float m = 0.f, sum = 0.f;
  float ctx[8] = {0.f, 0.f, 0.f, 0.f, 0.f, 0.f, 0.f, 0.f};

  auto att_step = [&](const float* kr) {
    float4 k0 = *(const float4*)kr;
    float4 k1 = *(const float4*)(kr + 4);
    float4 v0 = *(const float4*)(kr + 8);
    float4 v1 = *(const float4*)(kr + 12);
    float d = qa.x * k0.x;
    d = fmaf(qa.y, k0.y, d);
    d = fmaf(qa.z, k0.z, d);
    d = fmaf(qa.w, k0.w, d);
    d = fmaf(qb.x, k1.x, d);
    d = fmaf(qb.y, k1.y, d);
    d = fmaf(qb.z, k1.z, d);
    d = fmaf(qb.w, k1.w, d);
    d = fmaxf(d * rs, 0.f);
    float tt = __expf(-fabsf(d - m));
    bool up = d > m;
    float sc = up ? tt : 1.f;
    float e = up ? 1.f : tt;
    m = fmaxf(m, d);
    sum = fmaf(sum, sc, e);
    ctx[0] = fmaf(ctx[0], sc, e * v0.x);
    ctx[1] = fmaf(ctx[1], sc, e * v0.y);
    ctx[2] = fmaf(ctx[2], sc, e * v0.z);
    ctx[3] = fmaf(ctx[3], sc, e * v0.w);
    ctx[4] = fmaf(ctx[4], sc, e * v1.x);
    ctx[5] = fmaf(ctx[5], sc, e * v1.y);
    ctx[6] = fmaf(ctx[6], sc, e * v1.z);
    ctx[7] = fmaf(ctx[7], sc, e * v1.w);
  };

#pragma unroll 8
  for (int p = 0; p < 32; ++p) {
    int pi = __shfl(i0, p, 32);
    att_step(tab + (size_t)pi * 24 + 8);
  }
#pragma unroll
  for (int p = 0; p < 13; ++p) {
    int pi = __shfl(i1, p, 32);
    att_step(tab + (size_t)pi * 24 + 8);
  }
  att_step(auxb);
  att_step(auxb + 16);

  float inv = 1.f / sum;
  float logit = 0.f;
#pragma unroll
  for (int d0 = 0; d0 < 8; ++d0) {
    float c = ctx[d0] * inv;
    c = (c > 0.f) ? c : 0.01f * c;
    logit = fmaf(c, sc_w[d0], logit);
  }
  logit += sc_b[0];
  if (lane < PACK_N) out[(size_t)b * PACK_N + lane] = logit;
}

// ----------------------------------------------------------- fused kernel --
// 256 blocks x 512 threads. Phase B: 2-row ILP (rows r, r+64 share s_load'd
// weights -> 2x loads in flight to compensate the halved wave count).
__global__ __launch_bounds__(512) void k_fused(
    const int* __restrict__ pool, const int* __restrict__ pack,
    const float* __restrict__ wins, const float* __restrict__ ranks,
    const float* __restrict__ emb,
    const float* __restrict__ win_w, const float* __restrict__ win_b,
    const float* __restrict__ rank_w, const float* __restrict__ rank_b,
    const float* __restrict__ q_w, const float* __restrict__ k_w,
    const float* __restrict__ v_w,
    const float* __restrict__ sc_w, const float* __restrict__ sc_b,
    float* __restrict__ wt, float* __restrict__ tab,
    float* __restrict__ aux, float* __restrict__ out) {
  cg::grid_group grid = cg::this_grid();
  __shared__ float lds[12800];  // 51.2 KB
  int t = threadIdx.x;
  int blk = blockIdx.x;

  body_pre(blk, t, wins, ranks, win_w, win_b, rank_w, rank_b,
           q_w, k_w, v_w, wt, aux, lds);
  grid.sync();

  // ---- Phase B: tab, rows [blk*128, blk*128+128) ----
  {
    int lane = t & 63;
    int w = t >> 6;  // 0..7, e-slice [w*64, +64)
    int r0 = blk * 128 + lane;
    int r1 = r0 + 64;
    int c0 = (r0 < V_N) ? r0 : V_N - 1;
    int c1 = (r1 < V_N) ? r1 : V_N - 1;
    const float* a0 = emb + (size_t)c0 * E_N + w * 64;
    const float* a1 = emb + (size_t)c1 * E_N + w * 64;
    const float* wp = wt + (w * 64) * 24;
    float acc0[24], acc1[24];
#pragma unroll
    for (int j = 0; j < 24; ++j) { acc0[j] = 0.f; acc1[j] = 0.f; }
#pragma unroll 4
    for (int i = 0; i < 16; ++i) {
      float4 av0 = ((const float4*)a0)[i];
      float4 av1 = ((const float4*)a1)[i];
      float xs0[4] = {av0.x, av0.y, av0.z, av0.w};
      float xs1[4] = {av1.x, av1.y, av1.z, av1.w};
#pragma unroll
      for (int c = 0; c < 4; ++c) {
        const float* wr = wp + (i * 4 + c) * 24;
        float x0 = xs0[c], xr0 = fmaxf(x0, 0.f);
        float x1 = xs1[c], xr1 = fmaxf(x1, 0.f);
#pragma unroll
        for (int j = 0; j < 8; ++j) {
          acc0[j] = fmaf(x0, wr[j], acc0[j]);
          acc1[j] = fmaf(x1, wr[j], acc1[j]);
        }
#pragma unroll
        for (int j = 8; j < 24; ++j) {
          acc0[j] = fmaf(xr0, wr[j], acc0[j]);
          acc1[j] = fmaf(xr1, wr[j], acc1[j]);
        }
      }
    }
    // reduce+store rows [blk*128, +64) then [blk*128+64, +64)
    __syncthreads();
#pragma unroll
    for (int j = 0; j < 24; ++j) lds[w * 1600 + lane * 25 + j] = acc0[j];
    __syncthreads();
    for (int o = t; o < 1536; o += 512) {
      int row = o / 24, col = o - row * 24;
      int r_out = blk * 128 + row;
      if (r_out < V_N) {
        float v = 0.f;
#pragma unroll
        for (int s = 0; s < 8; ++s) v += lds[s * 1600 + row * 25 + col];
        tab[(size_t)r_out * 24 + col] = v;
      }
    }
    __syncthreads();
#pragma unroll
    for (int j = 0; j < 24; ++j) lds[w * 1600 + lane * 25 + j] = acc1[j];
    __syncthreads();
    for (int o = t; o < 1536; o += 512) {
      int row = o / 24, col = o - row * 24;
      int r_out = blk * 128 + 64 + row;
      if (r_out < V_N) {
        float v = 0.f;
#pragma unroll
        for (int s = 0; s < 8; ++s) v += lds[s * 1600 + row * 25 + col];
        tab[(size_t)r_out * 24 + col] = v;
      }
    }
  }
  grid.sync();

  body_main(blk, t, pool, pack, tab, aux, sc_w, sc_b, out);
}

// --------------------------------------------------------- fallback path ---
__global__ __launch_bounds__(512) void k_pre_fb(
    const float* __restrict__ wins, const float* __restrict__ ranks,
    const float* __restrict__ win_w, const float* __restrict__ win_b,
    const float* __restrict__ rank_w, const float* __restrict__ rank_b,
    const float* __restrict__ q_w, const float* __restrict__ k_w,
    const float* __restrict__ v_w,
    float* __restrict__ wt, float* __restrict__ aux) {
  __shared__ float lds[12800];
  body_pre(blockIdx.x, threadIdx.x, wins, ranks, win_w, win_b, rank_w, rank_b,
           q_w, k_w, v_w, wt, aux, lds);
}

// R3-verbatim build_tab (known-good): 469 blocks, 8 waves, 64-e slices.
__global__ __launch_bounds__(512) void k_tab_fb(const float* __restrict__ emb,
                                                const float* __restrict__ wt,
                                                float* __restrict__ tab) {
  __shared__ float red[8][64][25];
  int lane = threadIdx.x & 63;
  int w = threadIdx.x >> 6;
  int r = blockIdx.x * 64 + lane;
  float acc[24];
#pragma unroll
  for (int j = 0; j < 24; ++j) acc[j] = 0.f;
  if (r < V_N) {
    const float* a = emb + (size_t)r * E_N + w * 64;
    const float* wp = wt + (w * 64) * 24;
#pragma unroll 4
    for (int i = 0; i < 16; ++i) {
      float4 av = ((const float4*)a)[i];
      float xs[4] = {av.x, av.y, av.z, av.w};
#pragma unroll
      for (int c = 0; c < 4; ++c) {
        float x = xs[c];
        float xr = fmaxf(x, 0.f);
        const float* wr = wp + (i * 4 + c) * 24;
#pragma unroll
        for (int j = 0; j < 8; ++j) acc[j] = fmaf(x, wr[j], acc[j]);
#pragma unroll
        for (int j = 8; j < 24; ++j) acc[j] = fmaf(xr, wr[j], acc[j]);
      }
    }
  }
#pragma unroll
  for (int j = 0; j < 24; ++j) red[w][lane][j] = acc[j];
  __syncthreads();
  for (int o = threadIdx.x; o < 1536; o += 512) {
    int row = o / 24, col = o - row * 24;
    int r_out = blockIdx.x * 64 + row;
    if (r_out < V_N) {
      float v = 0.f;
#pragma unroll
      for (int s = 0; s < 8; ++s) v += red[s][row][col];
      tab[(size_t)r_out * 24 + col] = v;
    }
  }
}

__global__ __launch_bounds__(512) void k_main_fb(
    const int* __restrict__ pool, const int* __restrict__ pack,
    const float* __restrict__ tab, const float* __restrict__ aux,
    const float* __restrict__ sc_w, const float* __restrict__ sc_b,
    float* __restrict__ out) {
  body_main(blockIdx.x, threadIdx.x, pool, pack, tab, aux, sc_w, sc_b, out);
}

extern "C" void kernel_launch(void* const* d_in, const int* in_sizes, int n_in,
                              void* d_out, int out_size, void* d_ws, size_t ws_size,
                              hipStream_t stream) {
  const int* pool = (const int*)d_in[0];
  const int* pack = (const int*)d_in[1];
  const float* wins = (const float*)d_in[2];
  const float* ranks = (const float*)d_in[3];
  const float* emb = (const float*)d_in[4];
  const float* win_w = (const float*)d_in[5];
  const float* win_b = (const float*)d_in[6];
  const float* rank_w = (const float*)d_in[7];
  const float* rank_b = (const float*)d_in[8];
  const float* q_w = (const float*)d_in[9];
  const float* k_w = (const float*)d_in[10];
  const float* v_w = (const float*)d_in[11];
  const float* sc_w = (const float*)d_in[12];
  const float* sc_b = (const float*)d_in[13];

  float* ws = (float*)d_ws;
  float* wt = ws;
  float* tab = ws + WT_SZ;
  float* aux = ws + WT_SZ + TAB_SZ;
  float* out = (float*)d_out;

  void* kargs[] = {(void*)&pool, (void*)&pack, (void*)&wins, (void*)&ranks,
                   (void*)&emb, (void*)&win_w, (void*)&win_b, (void*)&rank_w,
                   (void*)&rank_b, (void*)&q_w, (void*)&k_w, (void*)&v_w,
                   (void*)&sc_w, (void*)&sc_b, (void*)&wt, (void*)&tab,
                   (void*)&aux, (void*)&out};
  hipError_t err = hipLaunchCooperativeKernel((const void*)k_fused, dim3(256),
                                              dim3(512), kargs, 0, stream);
  if (err != hipSuccess) {
    (void)hipGetLastError();  // clear sticky error from the failed launch
    hipLaunchKernelGGL(k_pre_fb, dim3(256), dim3(512), 0, stream,
                       wins, ranks, win_w, win_b, rank_w, rank_b,
                       q_w, k_w, v_w, wt, aux);
    hipLaunchKernelGGL(k_tab_fb, dim3((V_N + 63) / 64), dim3(512), 0, stream,
                       emb, wt, tab);
    hipLaunchKernelGGL(k_main_fb, dim3(256), dim3(512), 0, stream,
                       pool, pack, tab, aux, sc_w, sc_b, out);
  }
}